// Round 11
// baseline (231.978 us; speedup 1.0000x reference)
//
#include <hip/hip_runtime.h>
#include <hip/hip_bf16.h>
#include <stdint.h>

// Sizes: BS=64, M=1000, CLIP=512, D=512, N_WAYS=20, N_Z=8
// out = [logits (8,64,1000,20) | z (8,64,20,512) | mu (64,20,512) | scale (64,20,512)]

typedef __attribute__((ext_vector_type(8))) short short8;
typedef __attribute__((ext_vector_type(4))) float f32x4;

__device__ __forceinline__ float gelu_f(float x) {
    return 0.5f * x * (1.0f + erff(x * 0.70710678118654752440f));
}
__device__ __forceinline__ float softplus_f(float x) {
    return fmaxf(x, 0.0f) + log1pf(expf(-fabsf(x)));
}
__device__ __forceinline__ uint32_t cvt2(float a, float b) {  // pack 2 bf16 (RNE)
    __hip_bfloat162 h;
    h.x = __float2bfloat16(a);
    h.y = __float2bfloat16(b);
    uint32_t u; __builtin_memcpy(&u, &h, 4); return u;
}
__device__ __forceinline__ unsigned short f2bfu(float f) {
    __hip_bfloat16 h = __float2bfloat16(f);
    unsigned short u; __builtin_memcpy(&u, &h, 2); return u;
}
__device__ __forceinline__ float bfu2f(unsigned short u) {
    uint32_t v = (uint32_t)u << 16; float f; __builtin_memcpy(&f, &v, 4); return f;
}

// ---------------- threefry2x32 (partitionable) ----------------
__device__ __forceinline__ void threefry2x32(uint32_t k0, uint32_t k1,
                                             uint32_t x0, uint32_t x1,
                                             uint32_t& o0, uint32_t& o1) {
    uint32_t ks[3] = {k0, k1, k0 ^ k1 ^ 0x1BD11BDAu};
    x0 += ks[0]; x1 += ks[1];
    const uint32_t rot[8] = {13,15,26,6,17,29,16,24};
#pragma unroll
    for (int i = 0; i < 5; i++) {
#pragma unroll
        for (int j = 0; j < 4; j++) {
            uint32_t r = rot[(i & 1) * 4 + j];
            x0 += x1;
            x1 = (x1 << r) | (x1 >> (32 - r));
            x1 ^= x0;
        }
        x0 += ks[(i + 1) % 3];
        x1 += ks[(i + 2) % 3] + (uint32_t)(i + 1);
    }
    o0 = x0; o1 = x1;
}

__device__ __forceinline__ float bits_to_normal(uint32_t b) {
    float f = __uint_as_float((b >> 9) | 0x3F800000u) - 1.0f;
    const float lo = __uint_as_float(0xBF7FFFFFu);
    float u = fmaxf(lo, f * 2.0f + lo);
    return 1.41421356237309504880f * erfinvf(u);
}

// ---------------- batched prep: transposes, convs, dots, c0, counts -----------
// flat block id:
// [0,64)   WpT   [64,128) Wa1T   [128,256) Wa2T(C=1024)   [256,320) Wd1T
// [320,448) conv Wp -> Wpb   [448,576) conv Wd2 -> Wd2b
// [576,704) bv[d]=Wp[d,:]·bd2   [704,832) w2bp[k]=Wd2[k,:]·bp
// [832] c0 = bp·bd2            [833,897) cnt[b,cls]
__global__ __launch_bounds__(256) void prep_k(
    const float* __restrict__ Wp, const float* __restrict__ Wa1,
    const float* __restrict__ Wa2, const float* __restrict__ Wd1,
    const float* __restrict__ Wd2, const float* __restrict__ bp,
    const float* __restrict__ bd2, const int* __restrict__ y,
    unsigned short* __restrict__ WpTb, unsigned short* __restrict__ Wa1Tb,
    unsigned short* __restrict__ Wa2Tb, unsigned short* __restrict__ WdT1b,
    unsigned short* __restrict__ Wpb, unsigned short* __restrict__ Wd2b,
    float* __restrict__ bv, float* __restrict__ w2bp,
    float* __restrict__ c0, float* __restrict__ cnt)
{
    __shared__ float T[64][65];
    __shared__ int lc[32];
    __shared__ float ws4[4];
    const int f = blockIdx.x;
    const int tid = threadIdx.x;

    if (f < 320) {  // ---- transpose fp32 [512 x C] -> bf16 [C x 512]
        const float* src; unsigned short* dst; int C, t, xb, yb;
        if (f < 64)       { src = Wp;  dst = WpTb;  C = 512;  t = f;       xb = t & 7;  yb = t >> 3; }
        else if (f < 128) { src = Wa1; dst = Wa1Tb; C = 512;  t = f - 64;  xb = t & 7;  yb = t >> 3; }
        else if (f < 256) { src = Wa2; dst = Wa2Tb; C = 1024; t = f - 128; xb = t & 15; yb = t >> 4; }
        else              { src = Wd1; dst = WdT1b; C = 512;  t = f - 256; xb = t & 7;  yb = t >> 3; }
        const int r0 = yb * 64, cc0 = xb * 64;
        const int rr = tid >> 4, cc = (tid & 15) * 4;
#pragma unroll
        for (int l = 0; l < 4; l++) {
            int row = rr + l * 16;
            float4 v = *(const float4*)&src[(size_t)(r0 + row) * C + cc0 + cc];
            T[row][cc] = v.x; T[row][cc+1] = v.y; T[row][cc+2] = v.z; T[row][cc+3] = v.w;
        }
        __syncthreads();
#pragma unroll
        for (int l = 0; l < 4; l++) {
            int n = rr + l * 16;
            uint2 u;
            u.x = cvt2(T[cc][n], T[cc+1][n]);
            u.y = cvt2(T[cc+2][n], T[cc+3][n]);
            *(uint2*)&dst[(size_t)(cc0 + n) * 512 + r0 + cc] = u;
        }
    } else if (f < 576) {  // ---- plain conv fp32 -> bf16 (8 floats/thread)
        const float* src = (f < 448) ? Wp : Wd2;
        unsigned short* dst = (f < 448) ? Wpb : Wd2b;
        int t = (f < 448) ? f - 320 : f - 448;
        size_t i = ((size_t)t * 256 + tid) * 8;    // float index, 8 per thread
        float4 a = *(const float4*)&src[i];
        float4 b4 = *(const float4*)&src[i + 4];
        uint4 u;
        u.x = cvt2(a.x, a.y);  u.y = cvt2(a.z, a.w);
        u.z = cvt2(b4.x, b4.y); u.w = cvt2(b4.z, b4.w);
        *(uint4*)&dst[i] = u;
    } else if (f < 832) {  // ---- row dots (wave per row)
        const float* W = (f < 704) ? Wp : Wd2;
        const float* v = (f < 704) ? bd2 : bp;
        float* o = (f < 704) ? bv : w2bp;
        int t = (f < 704) ? f - 576 : f - 704;
        int wave = tid >> 6, lane = tid & 63;
        int r = t * 4 + wave;
        const float* row = W + (size_t)r * 512 + lane * 8;
        float4 x0 = *(const float4*)row;
        float4 x1 = *(const float4*)(row + 4);
        float4 v0 = *(const float4*)&v[lane * 8];
        float4 v1 = *(const float4*)&v[lane * 8 + 4];
        float s = x0.x*v0.x + x0.y*v0.y + x0.z*v0.z + x0.w*v0.w
                + x1.x*v1.x + x1.y*v1.y + x1.z*v1.z + x1.w*v1.w;
#pragma unroll
        for (int off = 32; off > 0; off >>= 1) s += __shfl_down(s, off, 64);
        if (lane == 0) o[r] = s;
    } else if (f == 832) {  // ---- c0 = bp . bd2
        float s = bp[tid] * bd2[tid] + bp[tid + 256] * bd2[tid + 256];
#pragma unroll
        for (int off = 32; off > 0; off >>= 1) s += __shfl_down(s, off, 64);
        int wave = tid >> 6, lane = tid & 63;
        if (lane == 0) ws4[wave] = s;
        __syncthreads();
        if (tid == 0) c0[0] = ws4[0] + ws4[1] + ws4[2] + ws4[3];
    } else {  // ---- class counts, exact int atomics
        int b = f - 833;
        if (tid < 32) lc[tid] = 0;
        __syncthreads();
        for (int m = tid; m < 1000; m += 256)
            atomicAdd(&lc[y[b * 1000 + m]], 1);
        __syncthreads();
        if (tid < 20) cnt[b * 20 + tid] = (float)lc[tid];
    }
}

// ---------------- onehot scatter as MFMA GEMM ---------------------------------
// A[b](20x512) = OH^T(20x1000) @ xc[b](1000x512), bf16 out, per block: 128 ch x 1 b.
// A-frag synthesized from y (LDS); xc chunk staged transposed [ch][m] bf16.
__global__ __launch_bounds__(256) void onehot_k(const float* __restrict__ xc,
                                                const int* __restrict__ y,
                                                unsigned short* __restrict__ Abf) {
    __shared__ unsigned short Xs[128 * 64];  // [ch][k] bf16, 128B rows, XOR-swz, 16 KB
    __shared__ int ys[1024];
    const int chb = blockIdx.x * 128;
    const int b = blockIdx.y;
    const int tid = threadIdx.x, lane = tid & 63, w = tid >> 6;
    const int chs = w * 32;            // wave-constant channel base (within 128)

    for (int i = tid; i < 1024; i += 256)
        ys[i] = (i < 1000) ? y[b * 1000 + i] : -1;

    f32x4 acc[2][2] = {};              // [mi: cls 0-15 / 16-31][ni: ch half]
    for (int step = 0; step < 16; step++) {
        const int k0 = step * 64;
        // global read: lane owns row m = k0+lane (clamped), 32 ch
        int m = k0 + lane; if (m > 999) m = 999;
        const float* src = xc + ((size_t)b * 1000 + m) * 512 + chb + chs;
        float x[32];
#pragma unroll
        for (int j8 = 0; j8 < 8; j8++) {
            float4 v = *(const float4*)(src + j8 * 4);
            x[j8*4+0]=v.x; x[j8*4+1]=v.y; x[j8*4+2]=v.z; x[j8*4+3]=v.w;
        }
        __syncthreads();   // previous compute done (and ys staged, first iter)
#pragma unroll
        for (int j = 0; j < 32; j++) {
            int ch = chs + j;
            *(unsigned short*)((char*)Xs + ch * 128 + ((lane * 2) ^ ((ch & 7) << 4)))
                = f2bfu(x[j]);
        }
        __syncthreads();
#pragma unroll
        for (int ks = 0; ks < 2; ks++) {
            int kb = ks * 32 + (lane >> 4) * 8;
            int4 yv0 = *(const int4*)&ys[k0 + kb];
            int4 yv1 = *(const int4*)&ys[k0 + kb + 4];
            int ya[8] = {yv0.x, yv0.y, yv0.z, yv0.w, yv1.x, yv1.y, yv1.z, yv1.w};
            short8 a[2];
#pragma unroll
            for (int mi = 0; mi < 2; mi++) {
                int cls = mi * 16 + (lane & 15);
#pragma unroll
                for (int e = 0; e < 8; e++)
                    a[mi][e] = (short)((ya[e] == cls) ? 0x3F80 : 0);
            }
            short8 bb[2];
#pragma unroll
            for (int ni = 0; ni < 2; ni++) {
                int ch = chs + ni * 16 + (lane & 15);
                bb[ni] = *(const short8*)((const char*)Xs + ch * 128 +
                           ((kb * 2) ^ ((ch & 7) << 4)));
            }
#pragma unroll
            for (int mi = 0; mi < 2; mi++)
#pragma unroll
                for (int ni = 0; ni < 2; ni++)
                    acc[mi][ni] = __builtin_amdgcn_mfma_f32_16x16x32_bf16(a[mi], bb[ni], acc[mi][ni], 0, 0, 0);
        }
    }
#pragma unroll
    for (int mi = 0; mi < 2; mi++) {
#pragma unroll
        for (int ni = 0; ni < 2; ni++) {
            int ch = chb + chs + ni * 16 + (lane & 15);
#pragma unroll
            for (int j = 0; j < 4; j++) {
                int cls = mi * 16 + (lane >> 4) * 4 + j;
                if (cls < 20)
                    Abf[((size_t)b * 20 + cls) * 512 + ch] = f2bfu(acc[mi][ni][j]);
            }
        }
    }
}

// ---------------- unified bf16 MFMA GEMM, 64x128 tile, K=512 ----------------
// A: bf16 [M x 512]; B: bf16 [Nn x 512] (row n = output col n).
// EPI 0: C0 = acc + bias (bf16)        EPI 1: C0 = relu(acc + extra[r]*bias[c]) (bf16)
// EPI 2: C0 = gelu(acc + bias) (bf16)  EPI 3: Nn=1024 split -> F0 = mu (f32), F1 = 0.01+0.99*softplus (f32)
template <int EPI>
__global__ __launch_bounds__(256) void gm2_k(const unsigned short* __restrict__ Abf,
                                             const unsigned short* __restrict__ Bbf,
                                             const float* __restrict__ bias,
                                             const float* __restrict__ extra,
                                             unsigned short* __restrict__ C0,
                                             float* __restrict__ F0,
                                             float* __restrict__ F1,
                                             int Nn) {
    __shared__ unsigned short As[64 * 64];    // 8 KB, XOR-swizzled
    __shared__ unsigned short Bs[128 * 64];   // 16 KB
    const int tid = threadIdx.x;
    const int lane = tid & 63, w = tid >> 6;
    const int row0 = blockIdx.y * 64, col0 = blockIdx.x * 128;
    f32x4 acc[4][2] = {};
    for (int k0 = 0; k0 < 512; k0 += 64) {
        {   // stage A (64 rows x 64 k)
            int row = tid >> 2, cs = (tid & 3) * 16;
            int swz = (row & 7) << 4;
            const unsigned short* src = Abf + (size_t)(row0 + row) * 512 + k0 + cs;
#pragma unroll
            for (int j = 0; j < 2; j++) {
                uint4 u = *(const uint4*)(src + j * 8);
                *(uint4*)((char*)As + row * 128 + (((cs + j * 8) * 2) ^ swz)) = u;
            }
        }
        {   // stage B (128 rows x 64 k)
            int row = tid >> 1, cs = (tid & 1) * 32;
            int swz = (row & 7) << 4;
            const unsigned short* src = Bbf + (size_t)(col0 + row) * 512 + k0 + cs;
#pragma unroll
            for (int j = 0; j < 4; j++) {
                uint4 u = *(const uint4*)(src + j * 8);
                *(uint4*)((char*)Bs + row * 128 + (((cs + j * 8) * 2) ^ swz)) = u;
            }
        }
        __syncthreads();
#pragma unroll
        for (int ks = 0; ks < 2; ks++) {
            short8 a[4], bb[2];
#pragma unroll
            for (int mi = 0; mi < 4; mi++) {
                int r = mi * 16 + (lane & 15);
                a[mi] = *(const short8*)((const char*)As + r * 128 +
                          (((ks * 32 + (lane >> 4) * 8) * 2) ^ ((r & 7) << 4)));
            }
#pragma unroll
            for (int ni = 0; ni < 2; ni++) {
                int n = w * 32 + ni * 16 + (lane & 15);
                bb[ni] = *(const short8*)((const char*)Bs + n * 128 +
                          (((ks * 32 + (lane >> 4) * 8) * 2) ^ ((n & 7) << 4)));
            }
#pragma unroll
            for (int mi = 0; mi < 4; mi++)
#pragma unroll
                for (int ni = 0; ni < 2; ni++)
                    acc[mi][ni] = __builtin_amdgcn_mfma_f32_16x16x32_bf16(a[mi], bb[ni], acc[mi][ni], 0, 0, 0);
        }
        __syncthreads();
    }
#pragma unroll
    for (int mi = 0; mi < 4; mi++) {
#pragma unroll
        for (int ni = 0; ni < 2; ni++) {
            int c = col0 + w * 32 + ni * 16 + (lane & 15);
            float bvv = bias ? bias[c] : 0.f;
#pragma unroll
            for (int j = 0; j < 4; j++) {
                int r = row0 + mi * 16 + (lane >> 4) * 4 + j;
                float v = acc[mi][ni][j];
                if (EPI == 0) {
                    v += bvv;
                    C0[(size_t)r * Nn + c] = f2bfu(v);
                } else if (EPI == 1) {
                    v += extra[r] * bvv;
                    C0[(size_t)r * Nn + c] = f2bfu(fmaxf(v, 0.f));
                } else if (EPI == 2) {
                    C0[(size_t)r * Nn + c] = f2bfu(gelu_f(v + bvv));
                } else {
                    v += bvv;
                    if (c < 512) F0[(size_t)r * 512 + c] = v;
                    else F1[(size_t)r * 512 + (c - 512)] = 0.01f + 0.99f * softplus_f(v);
                }
            }
        }
    }
}

// ---------------- z = mu + scale*eps ; emits fp32 z + bf16 zb ----------------
__global__ __launch_bounds__(256) void z2_k(const float* __restrict__ mu,
                                            const float* __restrict__ sc,
                                            float* __restrict__ z,
                                            unsigned short* __restrict__ zb) {
    const uint32_t NH = 2621440u;  // 5242880/2
    uint32_t i = blockIdx.x * 256u + threadIdx.x;
    if (i >= NH) return;
    uint32_t t0 = 2u * i;
    uint32_t o0, o1, p0, p1;
    threefry2x32(0u, 42u, 0u, t0, o0, o1);
    threefry2x32(0u, 42u, 0u, t0 + 1u, p0, p1);
    uint32_t r0 = t0 % 655360u;                  // even; r1 = r0+1 (no wrap)
    float2 mv = *(const float2*)&mu[r0];
    float2 sv = *(const float2*)&sc[r0];
    float z0 = mv.x + sv.x * bits_to_normal(o0 ^ o1);
    float z1 = mv.y + sv.y * bits_to_normal(p0 ^ p1);
    float2 zo; zo.x = z0; zo.y = z1;
    *(float2*)&z[t0] = zo;
    *(uint32_t*)&zb[t0] = cvt2(z0, z1);
}

// ---------------- beta[r] = Wg[r,:] . w2bp + c0 ----------------
__global__ __launch_bounds__(256) void beta2_k(const unsigned short* __restrict__ Wgb,
                                               const float* __restrict__ vec,
                                               const float* __restrict__ c0,
                                               float* __restrict__ beta) {
    int wave = threadIdx.x >> 6, lane = threadIdx.x & 63;
    int r = blockIdx.x * 4 + wave;
    short8 wv = *(const short8*)(Wgb + (size_t)r * 512 + lane * 8);
    float s = 0.f;
#pragma unroll
    for (int e = 0; e < 8; e++) s += vec[lane * 8 + e] * bfu2f((unsigned short)wv[e]);
#pragma unroll
    for (int o = 32; o > 0; o >>= 1) s += __shfl_down(s, o, 64);
    if (lane == 0) beta[r] = s + c0[0];
}

// ---------------- logits v3: one block = 128 q x ALL 160 (s,n) rows ----------
__global__ __launch_bounds__(512) void logits_mfma3_k(const float* __restrict__ Xq,
                                                      const unsigned short* __restrict__ Vb,
                                                      const float* __restrict__ beta,
                                                      float* __restrict__ out) {
    __shared__ unsigned short Vs[160 * 64];  // 20 KB
    __shared__ float bs[160];
    const int u = blockIdx.x + 8 * blockIdx.y;
    const int xcd = u & 7, idx = u >> 3;
    const int b = (idx & 7) * 8 + xcd;
    const int qh = idx >> 3;
    const int tid = threadIdx.x, lane = tid & 63, w = tid >> 6;
    const int wq = w >> 1, wn = w & 1;

    if (tid < 160) {
        int s = tid / 20, n = tid - s * 20;
        bs[tid] = beta[(size_t)(s * 64 + b) * 20 + n];
    }

    const int klane = (lane >> 4) * 8;
    const float* xp[2];
    int qb[2];
#pragma unroll
    for (int qs = 0; qs < 2; qs++) {
        qb[qs] = qh * 128 + wq * 32 + qs * 16;
        int qr = qb[qs] + (lane & 15);
        if (qr > 999) qr = 999;
        xp[qs] = Xq + ((size_t)b * 1000 + qr) * 512 + klane;
    }
    int vrow[5], vswz[5];
#pragma unroll
    for (int nf = 0; nf < 5; nf++) {
        int rr = wn * 80 + nf * 16 + (lane & 15);
        vrow[nf] = rr * 128;
        vswz[nf] = (rr & 7) << 4;
    }

    f32x4 acc[2][5] = {};
    for (int k0 = 0; k0 < 512; k0 += 64) {
        __syncthreads();
        for (int c = tid; c < 640; c += 512) {
            int row = c >> 2, off = (c & 3) * 32;
            int sdiv = row / 20;
            int row_g = row + sdiv * 1260 + b * 20;
            const unsigned short* src = Vb + (size_t)row_g * 512 + k0 + (c & 3) * 16;
            uint4 u0 = *(const uint4*)src;
            uint4 u1 = *(const uint4*)(src + 8);
            int swz = (row & 7) << 4;
            char* base = (char*)Vs + row * 128;
            *(uint4*)(base + (off ^ swz)) = u0;
            *(uint4*)(base + ((off + 16) ^ swz)) = u1;
        }
        __syncthreads();
#pragma unroll
        for (int ks = 0; ks < 2; ks++) {
            int kb = (ks * 32 + klane) * 2;
            short8 bf[5];
#pragma unroll
            for (int nf = 0; nf < 5; nf++)
                bf[nf] = *(const short8*)((const char*)Vs + vrow[nf] + (kb ^ vswz[nf]));
            short8 af[2];
#pragma unroll
            for (int qs = 0; qs < 2; qs++) {
                const float* p = xp[qs] + k0 + ks * 32;
                float4 v0 = *(const float4*)p;
                float4 v1 = *(const float4*)(p + 4);
                uint4 uu;
                uu.x = cvt2(v0.x, v0.y); uu.y = cvt2(v0.z, v0.w);
                uu.z = cvt2(v1.x, v1.y); uu.w = cvt2(v1.z, v1.w);
                __builtin_memcpy(&af[qs], &uu, 16);
            }
#pragma unroll
            for (int qs = 0; qs < 2; qs++)
#pragma unroll
                for (int nf = 0; nf < 5; nf++)
                    acc[qs][nf] = __builtin_amdgcn_mfma_f32_16x16x32_bf16(af[qs], bf[nf], acc[qs][nf], 0, 0, 0);
        }
    }

#pragma unroll
    for (int nf = 0; nf < 5; nf++) {
        int rl = wn * 80 + nf * 16 + (lane & 15);
        int s = rl / 20, n = rl - s * 20;
        float bb = bs[rl];
        size_t ob = (size_t)(s * 64 + b) * 20000;
#pragma unroll
        for (int qs = 0; qs < 2; qs++) {
#pragma unroll
            for (int j = 0; j < 4; j++) {
                int q = qb[qs] + (lane >> 4) * 4 + j;
                if (q < 1000)
                    out[ob + (size_t)q * 20 + n] = acc[qs][nf][j] + bb;
            }
        }
    }
}

extern "C" void kernel_launch(void* const* d_in, const int* in_sizes, int n_in,
                              void* d_out, int out_size, void* d_ws, size_t ws_size,
                              hipStream_t stream) {
    const float* x_context = (const float*)d_in[0];
    const int*   y_context = (const int*)d_in[1];
    const float* x_query   = (const float*)d_in[2];
    const float* Wp  = (const float*)d_in[3];
    const float* bp  = (const float*)d_in[4];
    const float* Wa1 = (const float*)d_in[5];
    const float* ba1 = (const float*)d_in[6];
    const float* Wa2 = (const float*)d_in[7];
    const float* ba2 = (const float*)d_in[8];
    const float* Wd1 = (const float*)d_in[9];
    const float* bd1 = (const float*)d_in[10];
    const float* Wd2 = (const float*)d_in[11];
    const float* bd2 = (const float*)d_in[12];

    float* out    = (float*)d_out;
    float* logits = out;                   // 10,240,000 f
    float* z      = out + 10240000;        // 5,242,880 f
    float* mu     = out + 15482880;        // 655,360 f
    float* sc     = out + 16138240;        // 655,360 f

    // workspace layout
    float* ws   = (float*)d_ws;
    float* cnt  = ws;                       // 1,280 f
    float* beta = cnt + 1280;               // 10,240 f
    float* bv   = beta + 10240;             // 512 f
    float* w2bp = bv + 512;                 // 512 f
    float* c0   = w2bp + 512;               // 1 f (+pad)
    unsigned short* WpTb  = (unsigned short*)(c0 + 63);       // 262,144 sh
    unsigned short* Wa1Tb = WpTb + 262144;                    // 262,144 sh
    unsigned short* Wa2Tb = Wa1Tb + 262144;                   // 524,288 sh
    unsigned short* WdT1b = Wa2Tb + 524288;                   // 262,144 sh
    unsigned short* Wpb   = WdT1b + 262144;                   // 262,144 sh
    unsigned short* Wd2b  = Wpb + 262144;                     // 262,144 sh
    unsigned short* Gtb   = Wd2b + 262144;                    // 262,144 sh
    unsigned short* Abf   = Gtb + 262144;                     // 655,360 sh
    unsigned short* combb = Abf + 655360;                     // 655,360 sh
    unsigned short* hb    = combb + 655360;                   // 655,360 sh
    unsigned short* zb    = hb + 655360;                      // 5,242,880 sh
    unsigned short* Vbf   = zb + 5242880;                     // 5,242,880 sh
    float* big = (float*)(Vbf + 5242880);                     // Wgb home
    unsigned short* Wgb = (unsigned short*)big;

    // 0) batched prep: transposes, convs, bv/w2bp/c0, class counts
    prep_k<<<dim3(897), 256, 0, stream>>>(Wp, Wa1, Wa2, Wd1, Wd2, bp, bd2, y_context,
                                          WpTb, Wa1Tb, Wa2Tb, WdT1b, Wpb, Wd2b,
                                          bv, w2bp, c0, cnt);
    // 0b) G[d,k] = Wp[d,:]·Wd2[k,:]  (512x512, bf16 out)
    gm2_k<0><<<dim3(4, 8), 256, 0, stream>>>(Wpb, Wd2b, nullptr, nullptr, Gtb, nullptr, nullptr, 512);
    // 1) A[b] = OH^T @ xc[b]  -> Abf (bf16 1280x512), via MFMA
    onehot_k<<<dim3(4, 64), 256, 0, stream>>>(x_context, y_context, Abf);
    // 3) comb = relu(A@Wp + cnt*bp)      [MFMA bf16]
    gm2_k<1><<<dim3(4, 20), 256, 0, stream>>>(Abf, WpTb, bp, cnt, combb, nullptr, nullptr, 512);
    // 4) h = gelu(comb@Wa1 + ba1)        [MFMA bf16]
    gm2_k<2><<<dim3(4, 20), 256, 0, stream>>>(combb, Wa1Tb, ba1, nullptr, hb, nullptr, nullptr, 512);
    // 5) stats = h@Wa2 + ba2 -> mu, scale (fp32 outputs)
    gm2_k<3><<<dim3(8, 20), 256, 0, stream>>>(hb, Wa2Tb, ba2, nullptr, nullptr, mu, sc, 1024);
    // 6) z (fp32 out) + zb (bf16)
    z2_k<<<dim3(10240), 256, 0, stream>>>(mu, sc, z, zb);
    // 7) Wg_bf = gelu(z@Wd1 + bd1)
    gm2_k<2><<<dim3(4, 160), 256, 0, stream>>>(zb, WdT1b, bd1, nullptr, Wgb, nullptr, nullptr, 512);
    // 8) V = Wg@G + bv   [folded Wf]
    gm2_k<0><<<dim3(4, 160), 256, 0, stream>>>(Wgb, Gtb, bv, nullptr, Vbf, nullptr, nullptr, 512);
    // 9) beta[r] = Wg[r,:]·w2bp + c0
    beta2_k<<<dim3(2560), 256, 0, stream>>>(Wgb, w2bp, c0, beta);
    // 10) logits
    logits_mfma3_k<<<dim3(8, 64), 512, 0, stream>>>(x_query, Vbf, beta, logits);
}